// Round 2
// 487.924 us; speedup vs baseline: 1.1226x; 1.1226x over previous
//
#include <hip/hip_runtime.h>
#include <math.h>

// Problem constants (from reference): S=2, B=16, C=80, H=W=128, N=128
constexpr int S_ = 2, B_ = 16, C_ = 80, H_ = 128, W_ = 128, N_ = 128;
constexpr int HW_ = H_ * W_;
constexpr long long BCHW_ = (long long)B_ * C_ * HW_;   // 20,971,520
constexpr int NV4_ = (int)(BCHW_ / 4);                  // 5,242,880 (exact)
#define EPSF 1e-4f

// focal grid: 2 slices (tl / br) x 1024 blocks x 256 threads, 20 f4/thread
constexpr int FOCAL_BPS = 1024;                   // blocks per slice
constexpr int F4_PER_BLOCK = NV4_ / FOCAL_BPS;    // 5120
constexpr int F4_PER_THREAD = F4_PER_BLOCK / 256; // 20
constexpr int BATCH = 5;                          // f4 per stream per batch
constexpr int NBATCH = F4_PER_THREAD / BATCH;     // 4

// Workspace float layout:
//  [0] pos_tl  [1] pos_br  [2] neg_tl  [3] neg_br  [4] npos_tl  [5] npos_br
//  [10..11] pull (s0,s1)   [12..13] push (s0,s1)
//  [14..15] sl1 tl (s0,s1) [16..17] sl1 br (s0,s1)
//  [18] num_off tl         [19] num_off br

__device__ inline float wave_reduce_sum(float v) {
#pragma unroll
  for (int off = 32; off > 0; off >>= 1) v += __shfl_down(v, off, 64);
  return v;
}

// Branchless focal contribution of one prediction x vs gt-derived (pos, negw).
// p = clamp(sigmoid(x), eps, 1-eps)
// pos:  log(p) * (1-p)^2          -> posacc
// neg:  log(1-p) * p^2 * negw     -> negacc
// Single log via select; weights selected via cndmask. No control flow ->
// the scheduler can hoist loads freely across elements.
__device__ inline void focal_elem_bl(float x, bool pos, float negw,
                                     float& posacc, float& negacc) {
  float t = __expf(-x);                      // e^{-x}
  float p = __builtin_amdgcn_rcpf(1.0f + t); // sigmoid, ~1ulp
  p = fminf(fmaxf(p, 1e-4f), 1.0f - 1e-4f);
  float om = 1.0f - p;
  float lq = __logf(pos ? p : om);
  posacc += pos ? lq * (om * om) : 0.0f;
  negacc += pos ? 0.0f : lq * (p * p) * negw;
}

__device__ inline void focal4(const float4& g, const float4& a, const float4& b,
                              float& pacc, float& nacc, float& npos) {
  const float ge[4] = {g.x, g.y, g.z, g.w};
  const float ae[4] = {a.x, a.y, a.z, a.w};
  const float be[4] = {b.x, b.y, b.z, b.w};
#pragma unroll
  for (int k = 0; k < 4; ++k) {
    const float gv = ge[k];
    const bool pos = (gv == 1.0f);
    const float omg = 1.0f - gv;
    const float negw = (omg * omg) * (omg * omg);
    npos += pos ? 1.0f : 0.0f;
    focal_elem_bl(ae[k], pos, negw, pacc, nacc);
    focal_elem_bl(be[k], pos, negw, pacc, nacc);
  }
}

// One slice (blockIdx.y): 0 = tl corner, 1 = br corner.
// Each thread streams 3 contiguous arrays: pred stack0, pred stack1, gt.
// BATCH=5 f4 per stream issued back-to-back (15 loads = ~60 VGPRs in
// flight) before any consumption -> deep MLP per wave. launch_bounds
// (256,4) budgets 128 VGPRs so the allocator keeps the batch live.
__global__ __launch_bounds__(256, 4) void focal_kernel(
    const float4* __restrict__ tl, const float4* __restrict__ br,
    const float4* __restrict__ gtl, const float4* __restrict__ gbr,
    float* __restrict__ ws) {
  const int slice = blockIdx.y;  // 0: tl, 1: br
  const float4* __restrict__ pred = (slice == 0) ? tl : br;
  const float4* __restrict__ gt = (slice == 0) ? gtl : gbr;

  float pacc = 0.0f, nacc = 0.0f, npos = 0.0f;

  int idx = blockIdx.x * F4_PER_BLOCK + threadIdx.x;

  for (int bt = 0; bt < NBATCH; ++bt) {
    float4 g[BATCH], a[BATCH], b[BATCH];
    // Interleave g/a/b per element so element i is consumable at
    // vmcnt(3*(BATCH-1-i)); all 15 loads issue before first use.
#pragma unroll
    for (int i = 0; i < BATCH; ++i) {
      const int j = idx + i * 256;
      g[i] = gt[j];
      a[i] = pred[j];
      b[i] = pred[NV4_ + j];
    }
#pragma unroll
    for (int i = 0; i < BATCH; ++i) {
      focal4(g[i], a[i], b[i], pacc, nacc, npos);
    }
    idx += BATCH * 256;
  }

  __shared__ float red[4][3];
  const int wave = threadIdx.x >> 6, lane = threadIdx.x & 63;
  float r0 = wave_reduce_sum(pacc);
  float r1 = wave_reduce_sum(nacc);
  float r2 = wave_reduce_sum(npos);
  if (lane == 0) { red[wave][0] = r0; red[wave][1] = r1; red[wave][2] = r2; }
  __syncthreads();
  if (threadIdx.x == 0) {
    float tp = red[0][0] + red[1][0] + red[2][0] + red[3][0];
    float tn = red[0][1] + red[1][1] + red[2][1] + red[3][1];
    float tc = red[0][2] + red[1][2] + red[2][2] + red[3][2];
    atomicAdd(&ws[0 + slice], tp);
    atomicAdd(&ws[2 + slice], tn);
    atomicAdd(&ws[4 + slice], tc);
  }
}

__device__ inline float sl1f(float d) {
  float a = fabsf(d);
  return (a < 1.0f) ? 0.5f * a * a : a - 0.5f;
}

__global__ __launch_bounds__(128) void ae_off_kernel(
    const float* __restrict__ tl_tags, const float* __restrict__ br_tags,
    const float* __restrict__ tl_offs, const float* __restrict__ br_offs,
    const int* __restrict__ tag_mask,
    const int* __restrict__ off_tl_mask, const int* __restrict__ off_br_mask,
    const float* __restrict__ gt_tl_off, const float* __restrict__ gt_br_off,
    const int* __restrict__ tl_tag_ind, const int* __restrict__ br_tag_ind,
    const int* __restrict__ tl_off_ind, const int* __restrict__ br_off_ind,
    float* __restrict__ ws) {
  const int s = blockIdx.x / B_;
  const int b = blockIdx.x % B_;
  const int n = threadIdx.x;

  __shared__ float sm_mean[N_];
  __shared__ float sm_m[N_];

  const float m = (tag_mask[b * N_ + n] != 0) ? 1.0f : 0.0f;
  const float t0 = tl_tags[(s * B_ + b) * HW_ + tl_tag_ind[b * N_ + n]];
  const float t1 = br_tags[(s * B_ + b) * HW_ + br_tag_ind[b * N_ + n]];
  const float mean = 0.5f * (t0 + t1);
  sm_mean[n] = mean;
  sm_m[n] = m;
  __syncthreads();

  float num = 0.0f;
  for (int j = 0; j < N_; ++j) num += sm_m[j];
  const float invn = 1.0f / (num + EPSF);
  const float d0 = t0 - mean, d1 = t1 - mean;
  const float pull_n = m * (d0 * d0 + d1 * d1) * invn;

  const float num2 = (num - 1.0f) * num;
  const float inv2 = 1.0f / (num2 + EPSF);
  float pacc = 0.0f;
  for (int j = 0; j < N_; ++j) {
    float dd = 1.0f - fabsf(mean - sm_mean[j]);
    dd = fmaxf(dd, 0.0f);
    pacc += sm_m[j] * (dd - invn);
  }
  const float push_n = m * pacc * inv2;

  // offsets (smooth-L1)
  const float mo_tl = (off_tl_mask[b * N_ + n] != 0) ? 1.0f : 0.0f;
  const float mo_br = (off_br_mask[b * N_ + n] != 0) ? 1.0f : 0.0f;
  const int io0 = tl_off_ind[b * N_ + n];
  const int io1 = br_off_ind[b * N_ + n];
  const float o00 = tl_offs[((s * B_ + b) * 2 + 0) * HW_ + io0];
  const float o01 = tl_offs[((s * B_ + b) * 2 + 1) * HW_ + io0];
  const float o10 = br_offs[((s * B_ + b) * 2 + 0) * HW_ + io1];
  const float o11 = br_offs[((s * B_ + b) * 2 + 1) * HW_ + io1];
  const float g00 = gt_tl_off[(b * N_ + n) * 2 + 0];
  const float g01 = gt_tl_off[(b * N_ + n) * 2 + 1];
  const float g10 = gt_br_off[(b * N_ + n) * 2 + 0];
  const float g11 = gt_br_off[(b * N_ + n) * 2 + 1];
  const float sl_tl = mo_tl * (sl1f(o00 - g00) + sl1f(o01 - g01));
  const float sl_br = mo_br * (sl1f(o10 - g10) + sl1f(o11 - g11));

  float vals[6] = {pull_n, push_n, sl_tl, sl_br,
                   (s == 0) ? mo_tl : 0.0f, (s == 0) ? mo_br : 0.0f};
  __shared__ float red[2][6];
  const int wave = n >> 6, lane = n & 63;
#pragma unroll
  for (int k = 0; k < 6; ++k) {
    float r = wave_reduce_sum(vals[k]);
    if (lane == 0) red[wave][k] = r;
  }
  __syncthreads();
  if (n == 0) {
    atomicAdd(&ws[10 + s], red[0][0] + red[1][0]);
    atomicAdd(&ws[12 + s], red[0][1] + red[1][1]);
    atomicAdd(&ws[14 + s], red[0][2] + red[1][2]);
    atomicAdd(&ws[16 + s], red[0][3] + red[1][3]);
    atomicAdd(&ws[18], red[0][4] + red[1][4]);
    atomicAdd(&ws[19], red[0][5] + red[1][5]);
  }
}

__global__ void finalize_kernel(const float* __restrict__ ws,
                                float* __restrict__ out) {
  if (threadIdx.x == 0 && blockIdx.x == 0) {
    const float npos_tl = ws[4], npos_br = ws[5];
    float focal = 0.0f;
    focal += (npos_tl > 0.0f) ? -(ws[0] + ws[2]) / npos_tl : -ws[2];
    focal += (npos_br > 0.0f) ? -(ws[1] + ws[3]) / npos_br : -ws[3];
    const float pull = ws[10] + ws[11];
    const float push = ws[12] + ws[13];
    const float off = (ws[14] + ws[15]) / (ws[18] + EPSF) +
                      (ws[16] + ws[17]) / (ws[19] + EPSF);
    out[0] = (focal + pull + push + off) * 0.5f;  // / S (=2)
  }
}

extern "C" void kernel_launch(void* const* d_in, const int* in_sizes, int n_in,
                              void* d_out, int out_size, void* d_ws, size_t ws_size,
                              hipStream_t stream) {
  const float* tl_heats   = (const float*)d_in[0];
  const float* br_heats   = (const float*)d_in[1];
  const float* tl_tags    = (const float*)d_in[2];
  const float* br_tags    = (const float*)d_in[3];
  const float* tl_offs    = (const float*)d_in[4];
  const float* br_offs    = (const float*)d_in[5];
  const float* gt_tl_heat = (const float*)d_in[6];
  const float* gt_br_heat = (const float*)d_in[7];
  const int* gt_tag_mask    = (const int*)d_in[8];
  const int* gt_off_tl_mask = (const int*)d_in[9];
  const int* gt_off_br_mask = (const int*)d_in[10];
  const float* gt_tl_off  = (const float*)d_in[11];
  const float* gt_br_off  = (const float*)d_in[12];
  const int* gt_tl_tag_ind = (const int*)d_in[13];
  const int* gt_br_tag_ind = (const int*)d_in[14];
  const int* gt_tl_off_ind = (const int*)d_in[15];
  const int* gt_br_off_ind = (const int*)d_in[16];

  float* ws = (float*)d_ws;
  float* out = (float*)d_out;

  hipMemsetAsync(ws, 0, 32 * sizeof(float), stream);

  dim3 fgrid(FOCAL_BPS, 2, 1);
  focal_kernel<<<fgrid, 256, 0, stream>>>(
      (const float4*)tl_heats, (const float4*)br_heats,
      (const float4*)gt_tl_heat, (const float4*)gt_br_heat, ws);

  ae_off_kernel<<<S_ * B_, N_, 0, stream>>>(
      tl_tags, br_tags, tl_offs, br_offs,
      gt_tag_mask, gt_off_tl_mask, gt_off_br_mask,
      gt_tl_off, gt_br_off,
      gt_tl_tag_ind, gt_br_tag_ind, gt_tl_off_ind, gt_br_off_ind, ws);

  finalize_kernel<<<1, 64, 0, stream>>>(ws, out);
}